// Round 17
// baseline (471.669 us; speedup 1.0000x reference)
//
#include <hip/hip_runtime.h>

// HetSAGE: 2-layer heterogeneous GraphSAGE, N=50000/type, E=500000/type, D=256.
// R16 consolidation: (1) fp8 snapshot fused into gemm-L0 epilogue (conv8
// kernel removed, -77 MB pass); (2) scan_bsum folded into scan_final (each
// block prefix-sums <=48 bsum ints itself); (3) gemm STAGE issued right after
// the barrier, before ds_reads (earlier load flight; same vmcnt accounting).

#define DDIM 256
#define EDIM 32
#define XK 544          // WT row stride (total K)
#define XA 288          // XB2 row stride: 256 agg + 32 et
#define BM 64           // GEMM row tile
#define KC 32           // K chunk
#define KSTEPS 17       // 544/32
#define SCHUNK 1024     // scan elements per block
#define LBUF 10240      // u16 per K-step buffer: A 2048 + B 8192

typedef unsigned short u16;
typedef unsigned char u8;
typedef short s16x8 __attribute__((ext_vector_type(8)));
typedef float f32x4 __attribute__((ext_vector_type(4)));
typedef u16 u16x4 __attribute__((ext_vector_type(4)));
typedef u16 u16x8 __attribute__((ext_vector_type(8)));

__device__ __forceinline__ u16 f2bf(float f) {
    unsigned u = __builtin_bit_cast(unsigned, f);
    u += 0x7FFF + ((u >> 16) & 1);           // RNE
    return (u16)(u >> 16);
}
__device__ __forceinline__ float bf2f(u16 u) {
    unsigned x = ((unsigned)u) << 16;
    return __builtin_bit_cast(float, x);
}

#define GLOAD16(gp, lp)                                                        \
    __builtin_amdgcn_global_load_lds(                                          \
        (const __attribute__((address_space(1))) unsigned int*)(gp),           \
        (__attribute__((address_space(3))) unsigned int*)(lp), 16, 0, 0)

// ---------------- CSR build (merged: blockIdx.y = edge type) ----------------
__global__ void count_kernel(const int* __restrict__ d0, const int* __restrict__ d1,
                             int E, int* __restrict__ c0, int* __restrict__ c1) {
    const int* dst = blockIdx.y ? d1 : d0;
    int* cnt = blockIdx.y ? c1 : c0;
    int e = blockIdx.x * blockDim.x + threadIdx.x;
    if (e < E) atomicAdd(&cnt[dst[e]], 1);
}

__global__ void scan_partial_kernel(const int* __restrict__ cnt0, const int* __restrict__ cnt1,
                                    int n, int* __restrict__ bsum, int nb) {
    const int* cnt = blockIdx.y ? cnt1 : cnt0;
    int base = blockIdx.x * SCHUNK + threadIdx.x * 4;
    int s = 0;
#pragma unroll
    for (int i = 0; i < 4; ++i) {
        int idx = base + i;
        if (idx < n) s += cnt[idx];
    }
#pragma unroll
    for (int m = 1; m < 64; m <<= 1) s += __shfl_xor(s, m);
    __shared__ int ws[4];
    int lane = threadIdx.x & 63, wid = threadIdx.x >> 6;
    if (lane == 0) ws[wid] = s;
    __syncthreads();
    if (threadIdx.x == 0) bsum[blockIdx.y * nb + blockIdx.x] = ws[0] + ws[1] + ws[2] + ws[3];
}

// per-block exclusive scan + self-computed bsum prefix -> rowstart, cursor
__global__ void scan_final_kernel(const int* __restrict__ cnt0, const int* __restrict__ cnt1,
                                  int n, const int* __restrict__ bsum, int nb,
                                  int* __restrict__ rs0, int* __restrict__ cur0,
                                  int* __restrict__ rs1, int* __restrict__ cur1) {
    const int* cnt = blockIdx.y ? cnt1 : cnt0;
    int* rs  = blockIdx.y ? rs1 : rs0;
    int* cur = blockIdx.y ? cur1 : cur0;
    int t = threadIdx.x;
    int bx = blockIdx.x;
    int lane = t & 63, wid = t >> 6;

    // exclusive prefix of bsum over blocks < bx (each wave redundantly)
    int bv = (lane < bx) ? bsum[blockIdx.y * nb + lane] : 0;   // bx <= 48 < 64
#pragma unroll
    for (int m = 1; m < 64; m <<= 1) bv += __shfl_xor(bv, m);
    int pre = bv;

    int base = bx * SCHUNK + t * 4;
    int v[4];
    int s = 0;
#pragma unroll
    for (int i = 0; i < 4; ++i) {
        int idx = base + i;
        v[i] = (idx < n) ? cnt[idx] : 0;
        s += v[i];
    }
    int ps = s;
#pragma unroll
    for (int m = 1; m < 64; m <<= 1) {
        int u = __shfl_up(ps, m);
        if (lane >= m) ps += u;
    }
    __shared__ int wsum[4];
    if (lane == 63) wsum[wid] = ps;
    __syncthreads();
    int wofs = 0;
    for (int i = 0; i < wid; ++i) wofs += wsum[i];
    int run = pre + wofs + ps - s;
#pragma unroll
    for (int i = 0; i < 4; ++i) {
        int idx = base + i;
        if (idx < n) {
            rs[idx] = run;
            cur[idx] = run;
            run += v[i];
        }
    }
    if (bx == nb - 1 && t == 255)
        rs[n] = pre + wsum[0] + wsum[1] + wsum[2] + wsum[3];
}

__global__ void fill_kernel(const int* __restrict__ ei0, const int* __restrict__ ei1, int E,
                            int* __restrict__ cu0, int* __restrict__ cu1,
                            int* __restrict__ sr0, int* __restrict__ sr1,
                            int* __restrict__ ed0, int* __restrict__ ed1) {
    const int* src = blockIdx.y ? ei1 : ei0;
    const int* dst = (blockIdx.y ? ei1 : ei0) + E;
    int* cursor = blockIdx.y ? cu1 : cu0;
    int* ssrc   = blockIdx.y ? sr1 : sr0;
    int* eid    = blockIdx.y ? ed1 : ed0;
    int e = blockIdx.x * blockDim.x + threadIdx.x;
    if (e < E) {
        int d = dst[e];
        int p = atomicAdd(&cursor[d], 1);
        ssrc[p] = src[e];
        eid[p] = e;
    }
}

// per-node et mean via CSR; 1 node/wave, 4 waves/block; merged types.
__global__ __launch_bounds__(256) void etgather_kernel(
    const float* __restrict__ et0, const float* __restrict__ et1,
    const int* __restrict__ rs0, const int* __restrict__ rs1,
    const int* __restrict__ ed0, const int* __restrict__ ed1,
    u16* __restrict__ em0, u16* __restrict__ em1, int n) {
    const float* et = blockIdx.y ? et1 : et0;
    const int* rs  = blockIdx.y ? rs1 : rs0;
    const int* eid = blockIdx.y ? ed1 : ed0;
    u16* etmean    = blockIdx.y ? em1 : em0;
    int node = blockIdx.x * 4 + (threadIdx.x >> 6);
    if (node >= n) return;
    int lane = threadIdx.x & 63;
    int c = lane & 31, eh = lane >> 5;
    int s0 = rs[node], s1 = rs[node + 1];
    float a = 0.f;
    for (int base = s0 + eh; base < s1; base += 8) {
        int idx[4];
#pragma unroll
        for (int j = 0; j < 4; ++j) {
            int e = base + 2 * j;
            idx[j] = eid[e < s1 ? e : s0];     // clamped: always a valid slot
        }
        float v[4];
#pragma unroll
        for (int j = 0; j < 4; ++j)
            v[j] = et[(size_t)idx[j] * EDIM + c];
#pragma unroll
        for (int j = 0; j < 4; ++j)
            if (base + 2 * j < s1) a += v[j];
    }
    a += __shfl_xor(a, 32);
    if (eh == 0) {
        int cn = s1 - s0;
        float ic = 1.0f / (float)(cn > 1 ? cn : 1);
        etmean[(size_t)node * EDIM + c] = f2bf(a * ic);
    }
}

// ---------------- bf16+fp8 prep (merged: y picks table) ----------------
__global__ void conv_h_kernel(const float* __restrict__ h0, const float* __restrict__ h1,
                              u16* __restrict__ hb0, u16* __restrict__ hb1,
                              unsigned* __restrict__ f80, unsigned* __restrict__ f81,
                              int total4) {
    const float* h = blockIdx.y ? h1 : h0;
    u16* hb = blockIdx.y ? hb1 : hb0;
    unsigned* f8 = blockIdx.y ? f81 : f80;
    int i = blockIdx.x * blockDim.x + threadIdx.x;
    int stride = gridDim.x * blockDim.x;
    for (; i < total4; i += stride) {
        float4 v = reinterpret_cast<const float4*>(h)[i];
        u16x4 o;
        o.x = f2bf(v.x); o.y = f2bf(v.y); o.z = f2bf(v.z); o.w = f2bf(v.w);
        reinterpret_cast<u16x4*>(hb)[i] = o;
        int p = __builtin_amdgcn_cvt_pk_fp8_f32(v.x, v.y, 0, false);
        p = __builtin_amdgcn_cvt_pk_fp8_f32(v.z, v.w, p, true);
        f8[i] = (unsigned)p;
    }
}

// WT[mat][c][k] = (k<512 ? W[k][c] : Wem[k-512][c]) as bf16.
// LDS 32x33 transpose tile -> k-contiguous (coalesced) writes.
__global__ __launch_bounds__(256) void wt_build_kernel(
    const float* W0, const float* W1, const float* W2,
    const float* W3, const float* EmA, const float* EmB,
    u16* __restrict__ WT) {
    __shared__ float tile[32][33];
    int mat = blockIdx.z;
    const float* W = (mat == 0) ? W0 : (mat == 1) ? W1 : (mat == 2) ? W2 : W3;
    const float* Em = (mat & 1) ? EmB : EmA;
    int k0 = blockIdx.x * 32, c0 = blockIdx.y * 32;
    int tx = threadIdx.x & 31, ty = threadIdx.x >> 5;
#pragma unroll
    for (int i = 0; i < 4; ++i) {
        int k = k0 + ty + i * 8;
        tile[ty + i * 8][tx] = (k < 512) ? W[(size_t)k * DDIM + c0 + tx]
                                         : Em[(size_t)(k - 512) * DDIM + c0 + tx];
    }
    __syncthreads();
#pragma unroll
    for (int i = 0; i < 4; ++i) {
        int c = c0 + ty + i * 8;
        WT[((size_t)mat * DDIM + c) * XK + k0 + tx] = f2bf(tile[tx][ty + i * 8]);
    }
}

// XB2 row = [bf16(mean agg) | bf16 etmean]; merged types.
// fp8 gather: 2 nodes/wave, 32 lanes/node, 8-B uint2 loads (256-B rows),
// 8-deep row batching; HW cvt_pk_f32_fp8 decode.
__global__ __launch_bounds__(256) void build_x_kernel(
    const u8* __restrict__ src0, const u8* __restrict__ src1,
    const int* __restrict__ rs0, const int* __restrict__ rs1,
    const int* __restrict__ ss0, const int* __restrict__ ss1,
    const u16* __restrict__ em0, const u16* __restrict__ em1,
    u16* __restrict__ xb0, u16* __restrict__ xb1, int n) {
    const u8* hf8src = blockIdx.y ? src1 : src0;
    const int* rs    = blockIdx.y ? rs1 : rs0;
    const int* ssrc  = blockIdx.y ? ss1 : ss0;
    const u16* etmean= blockIdx.y ? em1 : em0;
    u16* XB2         = blockIdx.y ? xb1 : xb0;
    int node = blockIdx.x * 8 + (threadIdx.x >> 5);
    if (node >= n) return;
    int t = threadIdx.x & 31;          // 8 B each: elements t*8 .. t*8+7
    int s0 = rs[node], s1 = rs[node + 1];
    int cdeg = s1 - s0;
    float ic = 1.0f / (float)(cdeg > 1 ? cdeg : 1);
    float a[8];
#pragma unroll
    for (int k = 0; k < 8; ++k) a[k] = 0.f;
    for (int base = s0; base < s1; base += 8) {
        int si[8];
#pragma unroll
        for (int j = 0; j < 8; ++j) {
            int e = base + j;
            si[j] = ssrc[e < s1 ? e : s0];     // clamped valid slot
        }
        uint2 v[8];
#pragma unroll
        for (int j = 0; j < 8; ++j)
            v[j] = *reinterpret_cast<const uint2*>(&hf8src[(size_t)si[j] * DDIM + t * 8]);
#pragma unroll
        for (int j = 0; j < 8; ++j)
            if (base + j < s1) {
                auto p0 = __builtin_amdgcn_cvt_pk_f32_fp8(v[j].x, false);
                auto p1 = __builtin_amdgcn_cvt_pk_f32_fp8(v[j].x, true);
                auto p2 = __builtin_amdgcn_cvt_pk_f32_fp8(v[j].y, false);
                auto p3 = __builtin_amdgcn_cvt_pk_f32_fp8(v[j].y, true);
                a[0] += p0[0]; a[1] += p0[1]; a[2] += p1[0]; a[3] += p1[1];
                a[4] += p2[0]; a[5] += p2[1]; a[6] += p3[0]; a[7] += p3[1];
            }
    }
    u16* xr = XB2 + (size_t)node * XA;
    u16x8 o;
#pragma unroll
    for (int k = 0; k < 8; ++k) o[k] = f2bf(a[k] * ic);
    *reinterpret_cast<u16x8*>(&xr[t * 8]) = o;
    if (t < 4)
        reinterpret_cast<u16x8*>(&xr[DDIM])[t] =
            reinterpret_cast<const u16x8*>(&etmean[(size_t)node * EDIM])[t];
}

// ---------------- MFMA GEMM + bias + LayerNorm (merged types) ----------------
// R13 config: 64x256 tile, 8 waves, 3-buffer LDS rotation, ONE barrier/step,
// counted vmcnt(3|2). STAGE issued right after the barrier (before ds_reads)
// for earlier load flight. Outputs: f32 / bf16 / fp8, each optional.
__global__ __launch_bounds__(512) void gemm_ln_kernel(
    const u16* __restrict__ hbA0, const u16* __restrict__ hbA1,
    const u16* __restrict__ X0, const u16* __restrict__ X1,
    const u16* __restrict__ WTa, const u16* __restrict__ WTb,
    const float* __restrict__ bv0, const float* __restrict__ bv1,
    const float* __restrict__ bm0, const float* __restrict__ bm1,
    const int* __restrict__ rs0, const int* __restrict__ rs1,
    const float* __restrict__ g0, const float* __restrict__ g1,
    const float* __restrict__ be0, const float* __restrict__ be1,
    float* __restrict__ out0, float* __restrict__ out1,
    u16* __restrict__ obf0, u16* __restrict__ obf1,
    u8* __restrict__ of80, u8* __restrict__ of81, int n) {
    const int ty = blockIdx.y;
    const u16* hbA = ty ? hbA1 : hbA0;
    const u16* XB2 = ty ? X1 : X0;
    const u16* WT  = ty ? WTb : WTa;
    const float* bvec = ty ? bv1 : bv0;
    const float* bem  = ty ? bm1 : bm0;
    const int* rs     = ty ? rs1 : rs0;
    const float* g    = ty ? g1 : g0;
    const float* beta = ty ? be1 : be0;
    float* out  = ty ? out1 : out0;
    u16* outbf  = ty ? obf1 : obf0;
    u8* outf8   = ty ? of81 : of80;

    __shared__ u16 L[3 * LBUF];              // 60 KB: per buf A 4 KB + B 16 KB
    __shared__ float2 mom[BM][4];            // 2 KB
    __shared__ float indls[BM];

    const int t = threadIdx.x;
    const int wid = t >> 6, lane = t & 63, lo = lane & 15, hi = lane >> 4;
    const int wr = wid >> 2, wc = wid & 3;   // 2M x 4N
    const int n0 = blockIdx.x * BM;

    if (t < BM) {
        int r = n0 + t;
        indls[t] = (r < n && (rs[r + 1] - rs[r]) > 0) ? 1.0f : 0.0f;
    }

    // A staging (first 4 waves; 256 lanes cover 64 rows x 4 slots)
    const int arow = (t & 255) >> 2;
    const int aslot = (t & 3) ^ ((arow >> 1) & 3);   // inverse-swizzled source
    const u16* agA = hbA + (size_t)(n0 + arow) * DDIM + aslot * 8;
    const u16* agX = XB2 + (size_t)(n0 + arow) * XA + aslot * 8;
    // B staging (all 8 waves, 2 loads each)
    const int br0 = t >> 2;
    const int bs0 = (t & 3) ^ ((br0 >> 1) & 3);
    const u16* bgp0 = WT + (size_t)br0 * XK + bs0 * 8;
    const int br1 = 128 + (t >> 2);
    const int bs1 = (t & 3) ^ ((br1 >> 1) & 3);
    const u16* bgp1 = WT + (size_t)br1 * XK + bs1 * 8;

    f32x4 acc[2][4];
#pragma unroll
    for (int i = 0; i < 2; ++i)
#pragma unroll
        for (int j = 0; j < 4; ++j) acc[i][j] = {0.f, 0.f, 0.f, 0.f};

    // waves 0-3 issue 3 loads per stage, waves 4-7 issue 2
    auto STAGE = [&](int buf, int kk) {
        u16* Lb = &L[buf * LBUF];
        if (wid < 4) {
            const u16* ap = (kk < 8) ? (agA + kk * KC) : (agX + (kk - 8) * KC);
            GLOAD16(ap, &Lb[wid * 512]);
        }
        int k0 = kk * KC;
        GLOAD16(bgp0 + k0, &Lb[2048 + wid * 512]);
        GLOAD16(bgp1 + k0, &Lb[2048 + 4096 + wid * 512]);
    };

    STAGE(0, 0);
    STAGE(1, 1);   // 2-deep prefetch in flight

#pragma unroll
    for (int ks = 0; ks < KSTEPS; ++ks) {
        // wait for stage ks (issued 2 steps ago); ks+1's loads stay in flight
        if (ks < KSTEPS - 1) {
            if (wid < 4) asm volatile("s_waitcnt vmcnt(3)" ::: "memory");
            else         asm volatile("s_waitcnt vmcnt(2)" ::: "memory");
        } else {
            asm volatile("s_waitcnt vmcnt(0)" ::: "memory");
        }
        __builtin_amdgcn_s_barrier();

        // issue next prefetch FIRST (earlier flight; buffer (ks+2)%3 was last
        // read at step ks-1, consumed before barrier ks -> safe)
        if (ks + 2 < KSTEPS) STAGE((ks + 2) % 3, ks + 2);

        const u16* Lb = &L[(ks % 3) * LBUF];
        s16x8 af[2], bf[4];
#pragma unroll
        for (int rt = 0; rt < 2; ++rt) {
            int row = wr * 32 + rt * 16 + lo;
            af[rt] = *reinterpret_cast<const s16x8*>(
                &Lb[row * KC + ((hi ^ ((row >> 1) & 3)) << 3)]);
        }
#pragma unroll
        for (int ct = 0; ct < 4; ++ct) {
            int c = wc * 64 + ct * 16 + lo;
            bf[ct] = *reinterpret_cast<const s16x8*>(
                &Lb[2048 + c * KC + ((hi ^ ((c >> 1) & 3)) << 3)]);
        }

        __builtin_amdgcn_s_setprio(1);
#pragma unroll
        for (int rt = 0; rt < 2; ++rt)
#pragma unroll
            for (int ct = 0; ct < 4; ++ct)
                acc[rt][ct] = __builtin_amdgcn_mfma_f32_16x16x32_bf16(
                    af[rt], bf[ct], acc[rt][ct], 0, 0, 0);
        __builtin_amdgcn_s_setprio(0);
    }

    float bb[4], bbem[4], gv[4], bev[4];
#pragma unroll
    for (int ct = 0; ct < 4; ++ct) {
        int c = wc * 64 + ct * 16 + lo;
        bb[ct] = bvec[c]; bbem[ct] = bem[c]; gv[ct] = g[c]; bev[ct] = beta[c];
    }
#pragma unroll
    for (int rt = 0; rt < 2; ++rt)
#pragma unroll
        for (int reg = 0; reg < 4; ++reg) {
            float indv = indls[wr * 32 + rt * 16 + hi * 4 + reg];
#pragma unroll
            for (int ct = 0; ct < 4; ++ct)
                acc[rt][ct][reg] += bb[ct] + indv * bbem[ct];
        }

#pragma unroll
    for (int rt = 0; rt < 2; ++rt)
#pragma unroll
        for (int reg = 0; reg < 4; ++reg) {
            float s = acc[rt][0][reg] + acc[rt][1][reg] + acc[rt][2][reg] + acc[rt][3][reg];
            float q = acc[rt][0][reg] * acc[rt][0][reg] + acc[rt][1][reg] * acc[rt][1][reg]
                    + acc[rt][2][reg] * acc[rt][2][reg] + acc[rt][3][reg] * acc[rt][3][reg];
#pragma unroll
            for (int m = 1; m < 16; m <<= 1) {
                s += __shfl_xor(s, m);
                q += __shfl_xor(q, m);
            }
            if (lo == 0) mom[wr * 32 + rt * 16 + hi * 4 + reg][wc] = make_float2(s, q);
        }
    __syncthreads();

#pragma unroll
    for (int rt = 0; rt < 2; ++rt)
#pragma unroll
        for (int reg = 0; reg < 4; ++reg) {
            int rl = wr * 32 + rt * 16 + hi * 4 + reg;
            float2 m0 = mom[rl][0], m1 = mom[rl][1], m2 = mom[rl][2], m3 = mom[rl][3];
            float s = m0.x + m1.x + m2.x + m3.x;
            float q = m0.y + m1.y + m2.y + m3.y;
            float mean = s * (1.0f / 256.0f);
            float var = q * (1.0f / 256.0f) - mean * mean;
            float inv = rsqrtf(var + 1e-5f);
            int r = n0 + rl;
            if (r < n) {
#pragma unroll
                for (int ct = 0; ct < 4; ++ct) {
                    float val = (acc[rt][ct][reg] - mean) * inv * gv[ct] + bev[ct];
                    size_t o = (size_t)r * DDIM + wc * 64 + ct * 16 + lo;
                    if (out) out[o] = val;
                    if (outbf) outbf[o] = f2bf(val);
                    if (outf8) {
                        int p = __builtin_amdgcn_cvt_pk_fp8_f32(val, val, 0, false);
                        outf8[o] = (u8)(p & 0xff);
                    }
                }
            }
        }
}

static inline size_t alignup(size_t x) { return (x + 1023) & ~(size_t)1023; }

extern "C" void kernel_launch(void* const* d_in, const int* in_sizes, int n_in,
                              void* d_out, int out_size, void* d_ws, size_t ws_size,
                              hipStream_t stream) {
    const float* h_user  = (const float*)d_in[0];
    const float* h_item  = (const float*)d_in[1];
    const float* et_ub   = (const float*)d_in[2];
    const float* et_bu   = (const float*)d_in[3];
    const float* W0_ub   = (const float*)d_in[4];
    const float* b0_ub   = (const float*)d_in[5];
    const float* W0_bu   = (const float*)d_in[6];
    const float* b0_bu   = (const float*)d_in[7];
    const float* W1_ub   = (const float*)d_in[8];
    const float* b1_ub   = (const float*)d_in[9];
    const float* W1_bu   = (const float*)d_in[10];
    const float* b1_bu   = (const float*)d_in[11];
    const float* bem_ub  = (const float*)d_in[13];
    const float* bem_bu  = (const float*)d_in[15];
    const float* g_u     = (const float*)d_in[16];
    const float* beta_u  = (const float*)d_in[17];
    const float* g_i     = (const float*)d_in[18];
    const float* beta_i  = (const float*)d_in[19];
    const int*   ei_ub   = (const int*)d_in[20];
    const int*   ei_bu   = (const int*)d_in[21];

    const int E = in_sizes[20] / 2;        // 500000
    const int n = in_sizes[0] / DDIM;      // 50000
    const int nPad = ((n + 127) / 128) * 128;   // 50048
    const int nb = (n + SCHUNK - 1) / SCHUNK;   // 49

    char* w = (char*)d_ws;
    size_t off = 0;
    auto take = [&](size_t bytes) -> void* {
        void* p = w + off;
        off = alignup(off + bytes);
        return p;
    };
    int*   cnt_ub   = (int*)take((size_t)n * 4);
    int*   cnt_bu   = (int*)take((size_t)n * 4);
    size_t zero_bytes = off;                     // only counts need zeroing
    int*   rs_ub    = (int*)take((size_t)(n + 1) * 4);
    int*   rs_bu    = (int*)take((size_t)(n + 1) * 4);
    int*   cur_ub   = (int*)take((size_t)n * 4);
    int*   cur_bu   = (int*)take((size_t)n * 4);
    int*   bsum     = (int*)take((size_t)2 * 64 * 4);
    int*   ssrc_ub  = (int*)take((size_t)E * 4);
    int*   ssrc_bu  = (int*)take((size_t)E * 4);
    int*   eid_ub   = (int*)take((size_t)E * 4);
    int*   eid_bu   = (int*)take((size_t)E * 4);
    u16*   hbu0     = (u16*)take((size_t)nPad * DDIM * 2);
    u16*   hbi0     = (u16*)take((size_t)nPad * DDIM * 2);
    u16*   hbu1     = (u16*)take((size_t)nPad * DDIM * 2);
    u16*   hbi1     = (u16*)take((size_t)nPad * DDIM * 2);
    u8*    f8u0     = (u8*)take((size_t)n * DDIM);
    u8*    f8i0     = (u8*)take((size_t)n * DDIM);
    u8*    f8u1     = (u8*)take((size_t)n * DDIM);
    u8*    f8i1     = (u8*)take((size_t)n * DDIM);
    u16*   etm_ub   = (u16*)take((size_t)n * EDIM * 2);
    u16*   etm_bu   = (u16*)take((size_t)n * EDIM * 2);
    u16*   XB2a     = (u16*)take((size_t)nPad * XA * 2);
    u16*   XB2b     = (u16*)take((size_t)nPad * XA * 2);
    u16*   WT       = (u16*)take((size_t)4 * DDIM * XK * 2);
    (void)ws_size; (void)n_in; (void)out_size;

    (void)hipMemsetAsync(w, 0, zero_bytes, stream);

    int eb = (E + 255) / 256;
    count_kernel<<<dim3(eb, 2), 256, 0, stream>>>(ei_ub + E, ei_bu + E, E, cnt_ub, cnt_bu);
    dim3 sg(nb, 2);
    scan_partial_kernel<<<sg, 256, 0, stream>>>(cnt_ub, cnt_bu, n, bsum, nb);
    scan_final_kernel<<<sg, 256, 0, stream>>>(cnt_ub, cnt_bu, n, bsum, nb,
                                              rs_ub, cur_ub, rs_bu, cur_bu);
    fill_kernel<<<dim3(eb, 2), 256, 0, stream>>>(ei_ub, ei_bu, E, cur_ub, cur_bu,
                                                 ssrc_ub, ssrc_bu, eid_ub, eid_bu);
    int ngb = (n + 3) / 4;
    etgather_kernel<<<dim3(ngb, 2), 256, 0, stream>>>(et_ub, et_bu, rs_ub, rs_bu,
                                                      eid_ub, eid_bu, etm_ub, etm_bu, n);

    dim3 wtg(XK / 32, DDIM / 32, 4);         // 17 x 8 x 4 transpose tiles
    wt_build_kernel<<<wtg, 256, 0, stream>>>(W0_ub, W0_bu, W1_ub, W1_bu,
                                             (const float*)d_in[12], (const float*)d_in[14], WT);

    float* hu_out = (float*)d_out;
    float* hi_out = (float*)d_out + (size_t)n * DDIM;
    int total4 = n * DDIM / 4;
    int gb = (n + BM - 1) / BM;              // 782
    int ngb8 = (n + 7) / 8;                  // 6250 (build_x: 8 nodes/block)
    const u16* WT0 = WT;
    const u16* WT1 = WT + (size_t)DDIM * XK;
    const u16* WT2 = WT + (size_t)2 * DDIM * XK;
    const u16* WT3 = WT + (size_t)3 * DDIM * XK;

    conv_h_kernel<<<dim3(1024, 2), 256, 0, stream>>>(h_user, h_item, hbu0, hbi0,
                                                     (unsigned*)f8u0, (unsigned*)f8i0, total4);

    // ---- layer 0 (bf16 + fp8 outputs fused into epilogue) ----
    build_x_kernel<<<dim3(ngb8, 2), 256, 0, stream>>>(f8u0, f8i0, rs_ub, rs_bu,
                                                      ssrc_ub, ssrc_bu, etm_ub, etm_bu,
                                                      XB2a, XB2b, n);
    gemm_ln_kernel<<<dim3(gb, 2), 512, 0, stream>>>(
        hbi0, hbu0, XB2a, XB2b, WT0, WT1, b0_ub, b0_bu, bem_ub, bem_bu,
        rs_ub, rs_bu, g_i, g_u, beta_i, beta_u,
        nullptr, nullptr, hbi1, hbu1, f8i1, f8u1, n);

    // ---- layer 1 (f32 outputs to d_out) ----
    build_x_kernel<<<dim3(ngb8, 2), 256, 0, stream>>>(f8u1, f8i1, rs_ub, rs_bu,
                                                      ssrc_ub, ssrc_bu, etm_ub, etm_bu,
                                                      XB2a, XB2b, n);
    gemm_ln_kernel<<<dim3(gb, 2), 512, 0, stream>>>(
        hbi1, hbu1, XB2a, XB2b, WT2, WT3, b1_ub, b1_bu, bem_ub, bem_bu,
        rs_ub, rs_bu, g_i, g_u, beta_i, beta_u,
        hi_out, hu_out, nullptr, nullptr, nullptr, nullptr, n);
}

// Round 18
// 463.131 us; speedup vs baseline: 1.0184x; 1.0184x over previous
//
#include <hip/hip_runtime.h>

// HetSAGE: 2-layer heterogeneous GraphSAGE, N=50000/type, E=500000/type, D=256.
// R17 = R15 (best gemm config: R13 K-loop, separate conv8, fp8 gather) +
// R16's scan merge. R16 post-mortem: fused fp8 epilogue = byte-scatter writes
// (+9us/dispatch on L0 gemms, worse than conv8's 13us streamed pass); both
// R16 gemm changes reverted.

#define DDIM 256
#define EDIM 32
#define XK 544          // WT row stride (total K)
#define XA 288          // XB2 row stride: 256 agg + 32 et
#define BM 64           // GEMM row tile
#define KC 32           // K chunk
#define KSTEPS 17       // 544/32
#define SCHUNK 1024     // scan elements per block
#define LBUF 10240      // u16 per K-step buffer: A 2048 + B 8192

typedef unsigned short u16;
typedef unsigned char u8;
typedef short s16x8 __attribute__((ext_vector_type(8)));
typedef float f32x4 __attribute__((ext_vector_type(4)));
typedef u16 u16x4 __attribute__((ext_vector_type(4)));
typedef u16 u16x8 __attribute__((ext_vector_type(8)));

__device__ __forceinline__ u16 f2bf(float f) {
    unsigned u = __builtin_bit_cast(unsigned, f);
    u += 0x7FFF + ((u >> 16) & 1);           // RNE
    return (u16)(u >> 16);
}
__device__ __forceinline__ float bf2f(u16 u) {
    unsigned x = ((unsigned)u) << 16;
    return __builtin_bit_cast(float, x);
}

#define GLOAD16(gp, lp)                                                        \
    __builtin_amdgcn_global_load_lds(                                          \
        (const __attribute__((address_space(1))) unsigned int*)(gp),           \
        (__attribute__((address_space(3))) unsigned int*)(lp), 16, 0, 0)

// ---------------- CSR build (merged: blockIdx.y = edge type) ----------------
__global__ void count_kernel(const int* __restrict__ d0, const int* __restrict__ d1,
                             int E, int* __restrict__ c0, int* __restrict__ c1) {
    const int* dst = blockIdx.y ? d1 : d0;
    int* cnt = blockIdx.y ? c1 : c0;
    int e = blockIdx.x * blockDim.x + threadIdx.x;
    if (e < E) atomicAdd(&cnt[dst[e]], 1);
}

__global__ void scan_partial_kernel(const int* __restrict__ cnt0, const int* __restrict__ cnt1,
                                    int n, int* __restrict__ bsum, int nb) {
    const int* cnt = blockIdx.y ? cnt1 : cnt0;
    int base = blockIdx.x * SCHUNK + threadIdx.x * 4;
    int s = 0;
#pragma unroll
    for (int i = 0; i < 4; ++i) {
        int idx = base + i;
        if (idx < n) s += cnt[idx];
    }
#pragma unroll
    for (int m = 1; m < 64; m <<= 1) s += __shfl_xor(s, m);
    __shared__ int ws[4];
    int lane = threadIdx.x & 63, wid = threadIdx.x >> 6;
    if (lane == 0) ws[wid] = s;
    __syncthreads();
    if (threadIdx.x == 0) bsum[blockIdx.y * nb + blockIdx.x] = ws[0] + ws[1] + ws[2] + ws[3];
}

// per-block exclusive scan + self-computed bsum prefix -> rowstart, cursor
__global__ void scan_final_kernel(const int* __restrict__ cnt0, const int* __restrict__ cnt1,
                                  int n, const int* __restrict__ bsum, int nb,
                                  int* __restrict__ rs0, int* __restrict__ cur0,
                                  int* __restrict__ rs1, int* __restrict__ cur1) {
    const int* cnt = blockIdx.y ? cnt1 : cnt0;
    int* rs  = blockIdx.y ? rs1 : rs0;
    int* cur = blockIdx.y ? cur1 : cur0;
    int t = threadIdx.x;
    int bx = blockIdx.x;
    int lane = t & 63, wid = t >> 6;

    // exclusive prefix of bsum over blocks < bx (each wave redundantly)
    int bv = (lane < bx) ? bsum[blockIdx.y * nb + lane] : 0;   // bx <= 48 < 64
#pragma unroll
    for (int m = 1; m < 64; m <<= 1) bv += __shfl_xor(bv, m);
    int pre = bv;

    int base = bx * SCHUNK + t * 4;
    int v[4];
    int s = 0;
#pragma unroll
    for (int i = 0; i < 4; ++i) {
        int idx = base + i;
        v[i] = (idx < n) ? cnt[idx] : 0;
        s += v[i];
    }
    int ps = s;
#pragma unroll
    for (int m = 1; m < 64; m <<= 1) {
        int u = __shfl_up(ps, m);
        if (lane >= m) ps += u;
    }
    __shared__ int wsum[4];
    if (lane == 63) wsum[wid] = ps;
    __syncthreads();
    int wofs = 0;
    for (int i = 0; i < wid; ++i) wofs += wsum[i];
    int run = pre + wofs + ps - s;
#pragma unroll
    for (int i = 0; i < 4; ++i) {
        int idx = base + i;
        if (idx < n) {
            rs[idx] = run;
            cur[idx] = run;
            run += v[i];
        }
    }
    if (bx == nb - 1 && t == 255)
        rs[n] = pre + wsum[0] + wsum[1] + wsum[2] + wsum[3];
}

__global__ void fill_kernel(const int* __restrict__ ei0, const int* __restrict__ ei1, int E,
                            int* __restrict__ cu0, int* __restrict__ cu1,
                            int* __restrict__ sr0, int* __restrict__ sr1,
                            int* __restrict__ ed0, int* __restrict__ ed1) {
    const int* src = blockIdx.y ? ei1 : ei0;
    const int* dst = (blockIdx.y ? ei1 : ei0) + E;
    int* cursor = blockIdx.y ? cu1 : cu0;
    int* ssrc   = blockIdx.y ? sr1 : sr0;
    int* eid    = blockIdx.y ? ed1 : ed0;
    int e = blockIdx.x * blockDim.x + threadIdx.x;
    if (e < E) {
        int d = dst[e];
        int p = atomicAdd(&cursor[d], 1);
        ssrc[p] = src[e];
        eid[p] = e;
    }
}

// per-node et mean via CSR; 1 node/wave, 4 waves/block; merged types.
__global__ __launch_bounds__(256) void etgather_kernel(
    const float* __restrict__ et0, const float* __restrict__ et1,
    const int* __restrict__ rs0, const int* __restrict__ rs1,
    const int* __restrict__ ed0, const int* __restrict__ ed1,
    u16* __restrict__ em0, u16* __restrict__ em1, int n) {
    const float* et = blockIdx.y ? et1 : et0;
    const int* rs  = blockIdx.y ? rs1 : rs0;
    const int* eid = blockIdx.y ? ed1 : ed0;
    u16* etmean    = blockIdx.y ? em1 : em0;
    int node = blockIdx.x * 4 + (threadIdx.x >> 6);
    if (node >= n) return;
    int lane = threadIdx.x & 63;
    int c = lane & 31, eh = lane >> 5;
    int s0 = rs[node], s1 = rs[node + 1];
    float a = 0.f;
    for (int base = s0 + eh; base < s1; base += 8) {
        int idx[4];
#pragma unroll
    for (int j = 0; j < 4; ++j) {
            int e = base + 2 * j;
            idx[j] = eid[e < s1 ? e : s0];     // clamped: always a valid slot
        }
        float v[4];
#pragma unroll
        for (int j = 0; j < 4; ++j)
            v[j] = et[(size_t)idx[j] * EDIM + c];
#pragma unroll
        for (int j = 0; j < 4; ++j)
            if (base + 2 * j < s1) a += v[j];
    }
    a += __shfl_xor(a, 32);
    if (eh == 0) {
        int cn = s1 - s0;
        float ic = 1.0f / (float)(cn > 1 ? cn : 1);
        etmean[(size_t)node * EDIM + c] = f2bf(a * ic);
    }
}

// ---------------- bf16+fp8 prep (merged: y picks table) ----------------
__global__ void conv_h_kernel(const float* __restrict__ h0, const float* __restrict__ h1,
                              u16* __restrict__ hb0, u16* __restrict__ hb1,
                              unsigned* __restrict__ f80, unsigned* __restrict__ f81,
                              int total4) {
    const float* h = blockIdx.y ? h1 : h0;
    u16* hb = blockIdx.y ? hb1 : hb0;
    unsigned* f8 = blockIdx.y ? f81 : f80;
    int i = blockIdx.x * blockDim.x + threadIdx.x;
    int stride = gridDim.x * blockDim.x;
    for (; i < total4; i += stride) {
        float4 v = reinterpret_cast<const float4*>(h)[i];
        u16x4 o;
        o.x = f2bf(v.x); o.y = f2bf(v.y); o.z = f2bf(v.z); o.w = f2bf(v.w);
        reinterpret_cast<u16x4*>(hb)[i] = o;
        int p = __builtin_amdgcn_cvt_pk_fp8_f32(v.x, v.y, 0, false);
        p = __builtin_amdgcn_cvt_pk_fp8_f32(v.z, v.w, p, true);
        f8[i] = (unsigned)p;
    }
}

// bf16 table -> fp8 table (for layer-1 gather sources)
__global__ void conv8_kernel(const u16* __restrict__ hb0, const u16* __restrict__ hb1,
                             unsigned* __restrict__ f80, unsigned* __restrict__ f81,
                             int total4) {
    const u16* hb = blockIdx.y ? hb1 : hb0;
    unsigned* f8 = blockIdx.y ? f81 : f80;
    int i = blockIdx.x * blockDim.x + threadIdx.x;
    int stride = gridDim.x * blockDim.x;
    for (; i < total4; i += stride) {
        u16x4 v = reinterpret_cast<const u16x4*>(hb)[i];
        int p = __builtin_amdgcn_cvt_pk_fp8_f32(bf2f(v.x), bf2f(v.y), 0, false);
        p = __builtin_amdgcn_cvt_pk_fp8_f32(bf2f(v.z), bf2f(v.w), p, true);
        f8[i] = (unsigned)p;
    }
}

// WT[mat][c][k] = (k<512 ? W[k][c] : Wem[k-512][c]) as bf16.
// LDS 32x33 transpose tile -> k-contiguous (coalesced) writes.
__global__ __launch_bounds__(256) void wt_build_kernel(
    const float* W0, const float* W1, const float* W2,
    const float* W3, const float* EmA, const float* EmB,
    u16* __restrict__ WT) {
    __shared__ float tile[32][33];
    int mat = blockIdx.z;
    const float* W = (mat == 0) ? W0 : (mat == 1) ? W1 : (mat == 2) ? W2 : W3;
    const float* Em = (mat & 1) ? EmB : EmA;
    int k0 = blockIdx.x * 32, c0 = blockIdx.y * 32;
    int tx = threadIdx.x & 31, ty = threadIdx.x >> 5;
#pragma unroll
    for (int i = 0; i < 4; ++i) {
        int k = k0 + ty + i * 8;
        tile[ty + i * 8][tx] = (k < 512) ? W[(size_t)k * DDIM + c0 + tx]
                                         : Em[(size_t)(k - 512) * DDIM + c0 + tx];
    }
    __syncthreads();
#pragma unroll
    for (int i = 0; i < 4; ++i) {
        int c = c0 + ty + i * 8;
        WT[((size_t)mat * DDIM + c) * XK + k0 + tx] = f2bf(tile[tx][ty + i * 8]);
    }
}

// XB2 row = [bf16(mean agg) | bf16 etmean]; merged types.
// fp8 gather: 2 nodes/wave, 32 lanes/node, 8-B uint2 loads (256-B rows),
// 8-deep row batching; HW cvt_pk_f32_fp8 decode.
__global__ __launch_bounds__(256) void build_x_kernel(
    const u8* __restrict__ src0, const u8* __restrict__ src1,
    const int* __restrict__ rs0, const int* __restrict__ rs1,
    const int* __restrict__ ss0, const int* __restrict__ ss1,
    const u16* __restrict__ em0, const u16* __restrict__ em1,
    u16* __restrict__ xb0, u16* __restrict__ xb1, int n) {
    const u8* hf8src = blockIdx.y ? src1 : src0;
    const int* rs    = blockIdx.y ? rs1 : rs0;
    const int* ssrc  = blockIdx.y ? ss1 : ss0;
    const u16* etmean= blockIdx.y ? em1 : em0;
    u16* XB2         = blockIdx.y ? xb1 : xb0;
    int node = blockIdx.x * 8 + (threadIdx.x >> 5);
    if (node >= n) return;
    int t = threadIdx.x & 31;          // 8 B each: elements t*8 .. t*8+7
    int s0 = rs[node], s1 = rs[node + 1];
    int cdeg = s1 - s0;
    float ic = 1.0f / (float)(cdeg > 1 ? cdeg : 1);
    float a[8];
#pragma unroll
    for (int k = 0; k < 8; ++k) a[k] = 0.f;
    for (int base = s0; base < s1; base += 8) {
        int si[8];
#pragma unroll
        for (int j = 0; j < 8; ++j) {
            int e = base + j;
            si[j] = ssrc[e < s1 ? e : s0];     // clamped valid slot
        }
        uint2 v[8];
#pragma unroll
        for (int j = 0; j < 8; ++j)
            v[j] = *reinterpret_cast<const uint2*>(&hf8src[(size_t)si[j] * DDIM + t * 8]);
#pragma unroll
        for (int j = 0; j < 8; ++j)
            if (base + j < s1) {
                auto p0 = __builtin_amdgcn_cvt_pk_f32_fp8(v[j].x, false);
                auto p1 = __builtin_amdgcn_cvt_pk_f32_fp8(v[j].x, true);
                auto p2 = __builtin_amdgcn_cvt_pk_f32_fp8(v[j].y, false);
                auto p3 = __builtin_amdgcn_cvt_pk_f32_fp8(v[j].y, true);
                a[0] += p0[0]; a[1] += p0[1]; a[2] += p1[0]; a[3] += p1[1];
                a[4] += p2[0]; a[5] += p2[1]; a[6] += p3[0]; a[7] += p3[1];
            }
    }
    u16* xr = XB2 + (size_t)node * XA;
    u16x8 o;
#pragma unroll
    for (int k = 0; k < 8; ++k) o[k] = f2bf(a[k] * ic);
    *reinterpret_cast<u16x8*>(&xr[t * 8]) = o;
    if (t < 4)
        reinterpret_cast<u16x8*>(&xr[DDIM])[t] =
            reinterpret_cast<const u16x8*>(&etmean[(size_t)node * EDIM])[t];
}

// ---------------- MFMA GEMM + bias + LayerNorm (merged types) ----------------
// R13 proven config: 64x256 tile, 8 waves (2M x 4N), 3-buffer LDS rotation,
// ONE s_barrier per K-step, counted vmcnt(3|2), s_setprio around MFMA.
__global__ __launch_bounds__(512) void gemm_ln_kernel(
    const u16* __restrict__ hbA0, const u16* __restrict__ hbA1,
    const u16* __restrict__ X0, const u16* __restrict__ X1,
    const u16* __restrict__ WTa, const u16* __restrict__ WTb,
    const float* __restrict__ bv0, const float* __restrict__ bv1,
    const float* __restrict__ bm0, const float* __restrict__ bm1,
    const int* __restrict__ rs0, const int* __restrict__ rs1,
    const float* __restrict__ g0, const float* __restrict__ g1,
    const float* __restrict__ be0, const float* __restrict__ be1,
    float* __restrict__ out0, float* __restrict__ out1,
    u16* __restrict__ obf0, u16* __restrict__ obf1, int n) {
    const int ty = blockIdx.y;
    const u16* hbA = ty ? hbA1 : hbA0;
    const u16* XB2 = ty ? X1 : X0;
    const u16* WT  = ty ? WTb : WTa;
    const float* bvec = ty ? bv1 : bv0;
    const float* bem  = ty ? bm1 : bm0;
    const int* rs     = ty ? rs1 : rs0;
    const float* g    = ty ? g1 : g0;
    const float* beta = ty ? be1 : be0;
    float* out  = ty ? out1 : out0;
    u16* outbf  = ty ? obf1 : obf0;

    __shared__ u16 L[3 * LBUF];              // 60 KB: per buf A 4 KB + B 16 KB
    __shared__ float2 mom[BM][4];            // 2 KB
    __shared__ float indls[BM];              // 64 KB total

    const int t = threadIdx.x;
    const int wid = t >> 6, lane = t & 63, lo = lane & 15, hi = lane >> 4;
    const int wr = wid >> 2, wc = wid & 3;   // 2M x 4N
    const int n0 = blockIdx.x * BM;

    if (t < BM) {
        int r = n0 + t;
        indls[t] = (r < n && (rs[r + 1] - rs[r]) > 0) ? 1.0f : 0.0f;
    }

    // A staging (first 4 waves; 256 lanes cover 64 rows x 4 slots)
    const int arow = (t & 255) >> 2;
    const int aslot = (t & 3) ^ ((arow >> 1) & 3);   // inverse-swizzled source
    const u16* agA = hbA + (size_t)(n0 + arow) * DDIM + aslot * 8;
    const u16* agX = XB2 + (size_t)(n0 + arow) * XA + aslot * 8;
    // B staging (all 8 waves, 2 loads each)
    const int br0 = t >> 2;
    const int bs0 = (t & 3) ^ ((br0 >> 1) & 3);
    const u16* bgp0 = WT + (size_t)br0 * XK + bs0 * 8;
    const int br1 = 128 + (t >> 2);
    const int bs1 = (t & 3) ^ ((br1 >> 1) & 3);
    const u16* bgp1 = WT + (size_t)br1 * XK + bs1 * 8;

    f32x4 acc[2][4];
#pragma unroll
    for (int i = 0; i < 2; ++i)
#pragma unroll
        for (int j = 0; j < 4; ++j) acc[i][j] = {0.f, 0.f, 0.f, 0.f};

    // waves 0-3 issue 3 loads per stage, waves 4-7 issue 2
    auto STAGE = [&](int buf, int kk) {
        u16* Lb = &L[buf * LBUF];
        if (wid < 4) {
            const u16* ap = (kk < 8) ? (agA + kk * KC) : (agX + (kk - 8) * KC);
            GLOAD16(ap, &Lb[wid * 512]);
        }
        int k0 = kk * KC;
        GLOAD16(bgp0 + k0, &Lb[2048 + wid * 512]);
        GLOAD16(bgp1 + k0, &Lb[2048 + 4096 + wid * 512]);
    };

    STAGE(0, 0);
    STAGE(1, 1);   // 2-deep prefetch in flight

#pragma unroll
    for (int ks = 0; ks < KSTEPS; ++ks) {
        // wait for stage ks (issued 2 steps ago); ks+1's loads stay in flight
        if (ks < KSTEPS - 1) {
            if (wid < 4) asm volatile("s_waitcnt vmcnt(3)" ::: "memory");
            else         asm volatile("s_waitcnt vmcnt(2)" ::: "memory");
        } else {
            asm volatile("s_waitcnt vmcnt(0)" ::: "memory");
        }
        __builtin_amdgcn_s_barrier();

        const u16* Lb = &L[(ks % 3) * LBUF];
        s16x8 af[2], bf[4];
#pragma unroll
        for (int rt = 0; rt < 2; ++rt) {
            int row = wr * 32 + rt * 16 + lo;
            af[rt] = *reinterpret_cast<const s16x8*>(
                &Lb[row * KC + ((hi ^ ((row >> 1) & 3)) << 3)]);
        }
#pragma unroll
        for (int ct = 0; ct < 4; ++ct) {
            int c = wc * 64 + ct * 16 + lo;
            bf[ct] = *reinterpret_cast<const s16x8*>(
                &Lb[2048 + c * KC + ((hi ^ ((c >> 1) & 3)) << 3)]);
        }
        if (ks + 2 < KSTEPS) STAGE((ks + 2) % 3, ks + 2);

        __builtin_amdgcn_s_setprio(1);
#pragma unroll
        for (int rt = 0; rt < 2; ++rt)
#pragma unroll
            for (int ct = 0; ct < 4; ++ct)
                acc[rt][ct] = __builtin_amdgcn_mfma_f32_16x16x32_bf16(
                    af[rt], bf[ct], acc[rt][ct], 0, 0, 0);
        __builtin_amdgcn_s_setprio(0);
    }

    float bb[4], bbem[4], gv[4], bev[4];
#pragma unroll
    for (int ct = 0; ct < 4; ++ct) {
        int c = wc * 64 + ct * 16 + lo;
        bb[ct] = bvec[c]; bbem[ct] = bem[c]; gv[ct] = g[c]; bev[ct] = beta[c];
    }
#pragma unroll
    for (int rt = 0; rt < 2; ++rt)
#pragma unroll
        for (int reg = 0; reg < 4; ++reg) {
            float indv = indls[wr * 32 + rt * 16 + hi * 4 + reg];
#pragma unroll
            for (int ct = 0; ct < 4; ++ct)
                acc[rt][ct][reg] += bb[ct] + indv * bbem[ct];
        }

#pragma unroll
    for (int rt = 0; rt < 2; ++rt)
#pragma unroll
        for (int reg = 0; reg < 4; ++reg) {
            float s = acc[rt][0][reg] + acc[rt][1][reg] + acc[rt][2][reg] + acc[rt][3][reg];
            float q = acc[rt][0][reg] * acc[rt][0][reg] + acc[rt][1][reg] * acc[rt][1][reg]
                    + acc[rt][2][reg] * acc[rt][2][reg] + acc[rt][3][reg] * acc[rt][3][reg];
#pragma unroll
            for (int m = 1; m < 16; m <<= 1) {
                s += __shfl_xor(s, m);
                q += __shfl_xor(q, m);
            }
            if (lo == 0) mom[wr * 32 + rt * 16 + hi * 4 + reg][wc] = make_float2(s, q);
        }
    __syncthreads();

#pragma unroll
    for (int rt = 0; rt < 2; ++rt)
#pragma unroll
        for (int reg = 0; reg < 4; ++reg) {
            int rl = wr * 32 + rt * 16 + hi * 4 + reg;
            float2 m0 = mom[rl][0], m1 = mom[rl][1], m2 = mom[rl][2], m3 = mom[rl][3];
            float s = m0.x + m1.x + m2.x + m3.x;
            float q = m0.y + m1.y + m2.y + m3.y;
            float mean = s * (1.0f / 256.0f);
            float var = q * (1.0f / 256.0f) - mean * mean;
            float inv = rsqrtf(var + 1e-5f);
            int r = n0 + rl;
            if (r < n) {
#pragma unroll
                for (int ct = 0; ct < 4; ++ct) {
                    float val = (acc[rt][ct][reg] - mean) * inv * gv[ct] + bev[ct];
                    size_t o = (size_t)r * DDIM + wc * 64 + ct * 16 + lo;
                    if (out) out[o] = val;
                    if (outbf) outbf[o] = f2bf(val);
                }
            }
        }
}

static inline size_t alignup(size_t x) { return (x + 1023) & ~(size_t)1023; }

extern "C" void kernel_launch(void* const* d_in, const int* in_sizes, int n_in,
                              void* d_out, int out_size, void* d_ws, size_t ws_size,
                              hipStream_t stream) {
    const float* h_user  = (const float*)d_in[0];
    const float* h_item  = (const float*)d_in[1];
    const float* et_ub   = (const float*)d_in[2];
    const float* et_bu   = (const float*)d_in[3];
    const float* W0_ub   = (const float*)d_in[4];
    const float* b0_ub   = (const float*)d_in[5];
    const float* W0_bu   = (const float*)d_in[6];
    const float* b0_bu   = (const float*)d_in[7];
    const float* W1_ub   = (const float*)d_in[8];
    const float* b1_ub   = (const float*)d_in[9];
    const float* W1_bu   = (const float*)d_in[10];
    const float* b1_bu   = (const float*)d_in[11];
    const float* bem_ub  = (const float*)d_in[13];
    const float* bem_bu  = (const float*)d_in[15];
    const float* g_u     = (const float*)d_in[16];
    const float* beta_u  = (const float*)d_in[17];
    const float* g_i     = (const float*)d_in[18];
    const float* beta_i  = (const float*)d_in[19];
    const int*   ei_ub   = (const int*)d_in[20];
    const int*   ei_bu   = (const int*)d_in[21];

    const int E = in_sizes[20] / 2;        // 500000
    const int n = in_sizes[0] / DDIM;      // 50000
    const int nPad = ((n + 127) / 128) * 128;   // 50048
    const int nb = (n + SCHUNK - 1) / SCHUNK;   // 49

    char* w = (char*)d_ws;
    size_t off = 0;
    auto take = [&](size_t bytes) -> void* {
        void* p = w + off;
        off = alignup(off + bytes);
        return p;
    };
    int*   cnt_ub   = (int*)take((size_t)n * 4);
    int*   cnt_bu   = (int*)take((size_t)n * 4);
    size_t zero_bytes = off;                     // only counts need zeroing
    int*   rs_ub    = (int*)take((size_t)(n + 1) * 4);
    int*   rs_bu    = (int*)take((size_t)(n + 1) * 4);
    int*   cur_ub   = (int*)take((size_t)n * 4);
    int*   cur_bu   = (int*)take((size_t)n * 4);
    int*   bsum     = (int*)take((size_t)2 * 64 * 4);
    int*   ssrc_ub  = (int*)take((size_t)E * 4);
    int*   ssrc_bu  = (int*)take((size_t)E * 4);
    int*   eid_ub   = (int*)take((size_t)E * 4);
    int*   eid_bu   = (int*)take((size_t)E * 4);
    u16*   hbu0     = (u16*)take((size_t)nPad * DDIM * 2);
    u16*   hbi0     = (u16*)take((size_t)nPad * DDIM * 2);
    u16*   hbu1     = (u16*)take((size_t)nPad * DDIM * 2);
    u16*   hbi1     = (u16*)take((size_t)nPad * DDIM * 2);
    u8*    f8u0     = (u8*)take((size_t)n * DDIM);
    u8*    f8i0     = (u8*)take((size_t)n * DDIM);
    u8*    f8u1     = (u8*)take((size_t)n * DDIM);
    u8*    f8i1     = (u8*)take((size_t)n * DDIM);
    u16*   etm_ub   = (u16*)take((size_t)n * EDIM * 2);
    u16*   etm_bu   = (u16*)take((size_t)n * EDIM * 2);
    u16*   XB2a     = (u16*)take((size_t)nPad * XA * 2);
    u16*   XB2b     = (u16*)take((size_t)nPad * XA * 2);
    u16*   WT       = (u16*)take((size_t)4 * DDIM * XK * 2);
    (void)ws_size; (void)n_in; (void)out_size;

    (void)hipMemsetAsync(w, 0, zero_bytes, stream);

    int eb = (E + 255) / 256;
    count_kernel<<<dim3(eb, 2), 256, 0, stream>>>(ei_ub + E, ei_bu + E, E, cnt_ub, cnt_bu);
    dim3 sg(nb, 2);
    scan_partial_kernel<<<sg, 256, 0, stream>>>(cnt_ub, cnt_bu, n, bsum, nb);
    scan_final_kernel<<<sg, 256, 0, stream>>>(cnt_ub, cnt_bu, n, bsum, nb,
                                              rs_ub, cur_ub, rs_bu, cur_bu);
    fill_kernel<<<dim3(eb, 2), 256, 0, stream>>>(ei_ub, ei_bu, E, cur_ub, cur_bu,
                                                 ssrc_ub, ssrc_bu, eid_ub, eid_bu);
    int ngb = (n + 3) / 4;
    etgather_kernel<<<dim3(ngb, 2), 256, 0, stream>>>(et_ub, et_bu, rs_ub, rs_bu,
                                                      eid_ub, eid_bu, etm_ub, etm_bu, n);

    dim3 wtg(XK / 32, DDIM / 32, 4);         // 17 x 8 x 4 transpose tiles
    wt_build_kernel<<<wtg, 256, 0, stream>>>(W0_ub, W0_bu, W1_ub, W1_bu,
                                             (const float*)d_in[12], (const float*)d_in[14], WT);

    float* hu_out = (float*)d_out;
    float* hi_out = (float*)d_out + (size_t)n * DDIM;
    int total4 = n * DDIM / 4;
    int gb = (n + BM - 1) / BM;              // 782
    int ngb8 = (n + 7) / 8;                  // 6250 (build_x: 8 nodes/block)
    const u16* WT0 = WT;
    const u16* WT1 = WT + (size_t)DDIM * XK;
    const u16* WT2 = WT + (size_t)2 * DDIM * XK;
    const u16* WT3 = WT + (size_t)3 * DDIM * XK;

    conv_h_kernel<<<dim3(1024, 2), 256, 0, stream>>>(h_user, h_item, hbu0, hbi0,
                                                     (unsigned*)f8u0, (unsigned*)f8i0, total4);

    // ---- layer 0 (bf16-only outputs into fresh buffers) ----
    build_x_kernel<<<dim3(ngb8, 2), 256, 0, stream>>>(f8u0, f8i0, rs_ub, rs_bu,
                                                      ssrc_ub, ssrc_bu, etm_ub, etm_bu,
                                                      XB2a, XB2b, n);
    gemm_ln_kernel<<<dim3(gb, 2), 512, 0, stream>>>(
        hbi0, hbu0, XB2a, XB2b, WT0, WT1, b0_ub, b0_bu, bem_ub, bem_bu,
        rs_ub, rs_bu, g_i, g_u, beta_i, beta_u,
        nullptr, nullptr, hbi1, hbu1, n);

    // fp8 snapshots of layer-0 outputs for the layer-1 gather
    conv8_kernel<<<dim3(1024, 2), 256, 0, stream>>>(hbu1, hbi1,
                                                    (unsigned*)f8u1, (unsigned*)f8i1, total4);

    // ---- layer 1 (f32 outputs to d_out) ----
    build_x_kernel<<<dim3(ngb8, 2), 256, 0, stream>>>(f8u1, f8i1, rs_ub, rs_bu,
                                                      ssrc_ub, ssrc_bu, etm_ub, etm_bu,
                                                      XB2a, XB2b, n);
    gemm_ln_kernel<<<dim3(gb, 2), 512, 0, stream>>>(
        hbi1, hbu1, XB2a, XB2b, WT2, WT3, b1_ub, b1_bu, bem_ub, bem_bu,
        rs_ub, rs_bu, g_i, g_u, beta_i, beta_u,
        hi_out, hu_out, nullptr, nullptr, n);
}